// Round 2
// baseline (1180.935 us; speedup 1.0000x reference)
//
#include <hip/hip_runtime.h>
#include <hip/hip_bf16.h>

using bf16 = __hip_bfloat16;
typedef __attribute__((ext_vector_type(8))) short bf16x8;
typedef __attribute__((ext_vector_type(4))) float f32x4;

static constexpr int TB  = 4;
static constexpr int TS  = 1024;
static constexpr int TD  = 1024;
static constexpr int TNH = 16;
static constexpr int TDH = 64;
static constexpr int TDI = 4096;

// ---------------- fallback: zero-fill output ----------------
__global__ __launch_bounds__(256) void zero_out_k(float* __restrict__ out, long n)
{
    long i = (long)blockIdx.x * 256 + threadIdx.x;
    if (i < n) out[i] = 0.0f;
}

// ---------------- elementwise fp32 -> bf16 ----------------
__global__ __launch_bounds__(256) void convert_f2b(const float* __restrict__ in,
                                                   bf16* __restrict__ out, long n)
{
    long i = (long)blockIdx.x * 256 + threadIdx.x;
    if (i < n) out[i] = __float2bfloat16(in[i]);
}

// ---------------- transpose fp32 [R,C] -> bf16 [C,R] ----------------
__global__ __launch_bounds__(256) void transpose_f2b(const float* __restrict__ in,
                                                     bf16* __restrict__ out,
                                                     int R, int C)
{
    __shared__ float tile[32][33];
    int c0 = blockIdx.x * 32, r0 = blockIdx.y * 32;
    int tx = threadIdx.x & 31, ty = threadIdx.x >> 5;
#pragma unroll
    for (int dy = 0; dy < 32; dy += 8)
        tile[ty + dy][tx] = in[(long)(r0 + ty + dy) * C + (c0 + tx)];
    __syncthreads();
#pragma unroll
    for (int dy = 0; dy < 32; dy += 8)
        out[(long)(c0 + ty + dy) * R + (r0 + tx)] = __float2bfloat16(tile[tx][ty + dy]);
}

// ---------------- transpose V [B,S,NH*DH] bf16 -> VT [B,NH,DH,S] bf16 ----------------
__global__ __launch_bounds__(256) void transpose_v(const bf16* __restrict__ V,
                                                   bf16* __restrict__ VT)
{
    __shared__ bf16 tile[32][33];
    int bn = blockIdx.z;
    int b = bn >> 4, n = bn & 15;
    const bf16* src = V + ((long)b * TS) * (TNH * TDH) + n * TDH;
    bf16* dst = VT + (long)bn * TDH * TS;
    int s0 = blockIdx.x * 32, d0 = blockIdx.y * 32;
    int tx = threadIdx.x & 31, ty = threadIdx.x >> 5;
#pragma unroll
    for (int dy = 0; dy < 32; dy += 8)
        tile[ty + dy][tx] = src[(long)(s0 + ty + dy) * (TNH * TDH) + (d0 + tx)];
    __syncthreads();
#pragma unroll
    for (int dy = 0; dy < 32; dy += 8)
        dst[(long)(d0 + ty + dy) * TS + (s0 + tx)] = tile[tx][ty + dy];
}

// ---------------- generic NT bf16 MFMA GEMM ----------------
// C[M,N] = A[M,K] (row-major, lda) @ Bt[N,K]^T (row-major, ldb), grid.z via strides.
// Epilogue: +bias[ncol], relu, +resid(fp32)/+residb(bf16), store bf16 Cb.
// Cb2 (if set) gets raw_acc + bias2 (dual-bias Q projection).
// relshift (requires M==N==S): writes Cb[i, j+i-(S-1)] += acc  (Transformer-XL shift,
// read-modify-write into the AC buffer; bijective per element).
#define BM 128
#define BN 128
#define BKK 32
#define LDSK (BKK + 8)

__global__ __launch_bounds__(256) void gemm_nt(
    const bf16* __restrict__ A, long lda, long sAz,
    const bf16* __restrict__ Bt, long ldb, long sBz,
    bf16* __restrict__ Cb, bf16* __restrict__ Cb2, long ldc, long sCz,
    const float* __restrict__ bias, const float* __restrict__ bias2,
    const float* __restrict__ resid, long ldr,
    const bf16* __restrict__ residb, long ldrb,
    int M, int N, int K, int relu, int relshift)
{
    __shared__ bf16 As[BM][LDSK];
    __shared__ bf16 Bs[BN][LDSK];
    const int z = blockIdx.z;
    A  += (long)z * sAz;
    Bt += (long)z * sBz;
    const long coff = (long)z * sCz;
    const int row0 = blockIdx.y * BM;
    const int col0 = blockIdx.x * BN;
    const int tid  = threadIdx.x;
    const int lane = tid & 63;
    const int wave = tid >> 6;
    const int wm = (wave & 1) * 64;
    const int wn = (wave >> 1) * 64;
    const int lr = lane & 15;
    const int lk = (lane >> 4) << 3;

    f32x4 acc[4][4] = {};

    const int m0  = tid >> 2;
    const int kc0 = (tid & 3) << 3;
    const int m1  = m0 + 64;

    for (int k0 = 0; k0 < K; k0 += BKK) {
        *(bf16x8*)(&As[m0][kc0]) =
            *(const bf16x8*)(A + (long)(row0 + m0) * lda + (k0 + kc0));
        *(bf16x8*)(&As[m1][kc0]) =
            *(const bf16x8*)(A + (long)(row0 + m1) * lda + (k0 + kc0));
        bf16x8 v0 = {0, 0, 0, 0, 0, 0, 0, 0};
        bf16x8 v1 = v0;
        if (col0 + m0 < N)
            v0 = *(const bf16x8*)(Bt + (long)(col0 + m0) * ldb + (k0 + kc0));
        if (col0 + m1 < N)
            v1 = *(const bf16x8*)(Bt + (long)(col0 + m1) * ldb + (k0 + kc0));
        *(bf16x8*)(&Bs[m0][kc0]) = v0;
        *(bf16x8*)(&Bs[m1][kc0]) = v1;
        __syncthreads();

        bf16x8 af[4], bfr[4];
#pragma unroll
        for (int t = 0; t < 4; ++t) af[t]  = *(const bf16x8*)(&As[wm + t * 16 + lr][lk]);
#pragma unroll
        for (int t = 0; t < 4; ++t) bfr[t] = *(const bf16x8*)(&Bs[wn + t * 16 + lr][lk]);
#pragma unroll
        for (int i = 0; i < 4; ++i)
#pragma unroll
            for (int j = 0; j < 4; ++j)
                acc[i][j] = __builtin_amdgcn_mfma_f32_16x16x32_bf16(
                    af[i], bfr[j], acc[i][j], 0, 0, 0);
        __syncthreads();
    }

    const int lq = (lane >> 4) << 2;
#pragma unroll
    for (int i = 0; i < 4; ++i) {
#pragma unroll
        for (int j = 0; j < 4; ++j) {
#pragma unroll
            for (int rg = 0; rg < 4; ++rg) {
                int mrow = row0 + wm + i * 16 + lq + rg;
                int ncol = col0 + wn + j * 16 + lr;
                if (ncol >= N) continue;
                float vraw = acc[i][j][rg];
                float v = vraw;
                if (bias)   v += bias[ncol];
                if (relu)   v = fmaxf(v, 0.0f);
                if (resid)  v += resid[(long)mrow * ldr + ncol];
                if (residb) v += __bfloat162float(residb[(long)mrow * ldrb + ncol]);
                long cidx;
                if (relshift) {
                    int c = ncol + mrow - (N - 1);
                    if (c < 0) continue;
                    cidx = coff + (long)mrow * ldc + c;
                    v += __bfloat162float(Cb[cidx]);
                } else {
                    cidx = coff + (long)mrow * ldc + ncol;
                }
                Cb[cidx] = __float2bfloat16(v);
                if (Cb2) Cb2[cidx] = __float2bfloat16(vraw + (bias2 ? bias2[ncol] : 0.0f));
            }
        }
    }
}

// ---------------- causal softmax over combined scores, in-place bf16 ----------------
// SC[n,i,j] holds ac+bd_shifted for j<=i (garbage for j>i). Softmax over j in [0,i],
// writes P (bf16) in place; zeros for j>i. One block per (row i, head n).
__global__ __launch_bounds__(256) void softmax_rel(bf16* __restrict__ SC, float scale)
{
    const int S = TS;
    int i = blockIdx.x, n = blockIdx.y;
    long rowoff = ((long)n * S + i) * S;
    bf16* p = SC + rowoff;
    int tid = threadIdx.x;
    int L = i + 1;
    int wave = tid >> 6;

    float sv[4];
    float mx = -1e30f;
#pragma unroll
    for (int it = 0; it < 4; ++it) {
        int j = tid + it * 256;
        float s = -1e30f;
        if (j < L) s = __bfloat162float(p[j]) * scale;
        sv[it] = s;
        mx = fmaxf(mx, s);
    }
    for (int off = 32; off; off >>= 1) mx = fmaxf(mx, __shfl_xor(mx, off));
    __shared__ float sm[4];
    if ((tid & 63) == 0) sm[wave] = mx;
    __syncthreads();
    mx = fmaxf(fmaxf(sm[0], sm[1]), fmaxf(sm[2], sm[3]));

    float e[4];
    float sum = 0.0f;
#pragma unroll
    for (int it = 0; it < 4; ++it) {
        int j = tid + it * 256;
        float ev = (j < L) ? expf(sv[it] - mx) : 0.0f;
        e[it] = ev;
        sum += ev;
    }
    for (int off = 32; off; off >>= 1) sum += __shfl_xor(sum, off);
    __shared__ float ss[4];
    if ((tid & 63) == 0) ss[wave] = sum;
    __syncthreads();
    sum = ss[0] + ss[1] + ss[2] + ss[3];
    float inv = 1.0f / sum;
#pragma unroll
    for (int it = 0; it < 4; ++it) {
        int j = tid + it * 256;
        p[j] = __float2bfloat16(e[it] * inv);
    }
}

// ---------------- LayerNorm over D=1024, bf16 in, fp32 and/or bf16 out ----------------
__global__ __launch_bounds__(256) void layernorm_b(const bf16* __restrict__ X,
                                                   const float* __restrict__ g,
                                                   const float* __restrict__ bta,
                                                   float* __restrict__ Yf,
                                                   bf16* __restrict__ Yb)
{
    const int D = TD;
    long row = blockIdx.x;
    const bf16* x = X + row * D;
    int tid = threadIdx.x;
    int wave = tid >> 6;

    float v[4], s = 0.0f;
#pragma unroll
    for (int it = 0; it < 4; ++it) { v[it] = __bfloat162float(x[tid + it * 256]); s += v[it]; }
    for (int off = 32; off; off >>= 1) s += __shfl_xor(s, off);
    __shared__ float sm[8];
    if ((tid & 63) == 0) sm[wave] = s;
    __syncthreads();
    float mean = (sm[0] + sm[1] + sm[2] + sm[3]) * (1.0f / D);

    float var = 0.0f;
#pragma unroll
    for (int it = 0; it < 4; ++it) { float d = v[it] - mean; var += d * d; }
    for (int off = 32; off; off >>= 1) var += __shfl_xor(var, off);
    if ((tid & 63) == 0) sm[4 + wave] = var;
    __syncthreads();
    var = (sm[4] + sm[5] + sm[6] + sm[7]) * (1.0f / D);
    float rinv = rsqrtf(var + 1e-5f);

#pragma unroll
    for (int it = 0; it < 4; ++it) {
        int c = tid + it * 256;
        float o = (v[it] - mean) * rinv * g[c] + bta[c];
        if (Yf) Yf[row * D + c] = o;
        if (Yb) Yb[row * D + c] = __float2bfloat16(o);
    }
}

extern "C" void kernel_launch(void* const* d_in, const int* in_sizes, int n_in,
                              void* d_out, int out_size, void* d_ws, size_t ws_size,
                              hipStream_t stream)
{
    const float* w      = (const float*)d_in[0];
    const float* r      = (const float*)d_in[1];
    const float* w_bias = (const float*)d_in[2];
    const float* r_bias = (const float*)d_in[3];
    const float* Wq     = (const float*)d_in[4];
    const float* Wk     = (const float*)d_in[5];
    const float* Wv     = (const float*)d_in[6];
    const float* Wr     = (const float*)d_in[7];
    const float* Wo     = (const float*)d_in[8];
    const float* ln1_g  = (const float*)d_in[9];
    const float* ln1_b  = (const float*)d_in[10];
    const float* W1     = (const float*)d_in[11];
    const float* b1     = (const float*)d_in[12];
    const float* W2     = (const float*)d_in[13];
    const float* b2     = (const float*)d_in[14];
    const float* ln2_g  = (const float*)d_in[15];
    const float* ln2_b  = (const float*)d_in[16];
    float* out = (float*)d_out;

    const int  B = TB, S = TS, D = TD, NH = TNH, DH = TDH, DI = TDI;
    const long MS = (long)B * S;            // 4096
    const long ND = (long)MS * D;           // 4M elems

    // ---- workspace carve-up (~122 MB) ----
    char* base = (char*)d_ws;
    size_t off = 0;
    auto alloc = [&](size_t bytes) -> void* {
        void* p = base + off;
        off += (bytes + 255) & ~(size_t)255;
        return p;
    };
    bf16* wqT  = (bf16*)alloc(2UL * D * D);
    bf16* wkT  = (bf16*)alloc(2UL * D * D);
    bf16* wvT  = (bf16*)alloc(2UL * D * D);
    bf16* wrT  = (bf16*)alloc(2UL * D * D);
    bf16* woT  = (bf16*)alloc(2UL * D * D);
    bf16* w1T  = (bf16*)alloc(2UL * D * DI);
    bf16* w2T  = (bf16*)alloc(2UL * DI * D);
    bf16* bufA = (bf16*)alloc(2UL * ND);            // w_bf, later attn_vec
    bf16* bufB = (bf16*)alloc(2UL * ND);            // r_bf, later x_bf
    bf16* Qw   = (bf16*)alloc(2UL * ND);
    bf16* Qr   = (bf16*)alloc(2UL * ND);
    bf16* Kb   = (bf16*)alloc(2UL * ND);
    bf16* RRb  = (bf16*)alloc(2UL * ND);
    bf16* VT   = (bf16*)alloc(2UL * ND);
    bf16* R0   = (bf16*)alloc(2UL * NH * S * S);    // Vb -> SC(scores/P) -> h (32 MB)
    bf16* yb   = (bf16*)alloc(2UL * ND);
    size_t need = off;
    (void)in_sizes; (void)n_in; (void)out_size;

    if (ws_size < need) {   // graceful degrade: clean numeric failure, not a fault
        zero_out_k<<<dim3((unsigned)((ND + 255) / 256)), 256, 0, stream>>>(out, ND);
        return;
    }

    bf16* w_bf = bufA;  bf16* attn_vec = bufA;
    bf16* r_bf = bufB;  bf16* x_bf     = bufB;
    bf16* Vb   = R0;    bf16* SC       = R0;    bf16* h = R0;

    auto launch_gemm = [&](const bf16* A, long lda, long sAz,
                           const bf16* Bt, long ldb, long sBz,
                           bf16* Cb, bf16* Cb2, long ldc, long sCz,
                           const float* bias, const float* bias2,
                           const float* resid, long ldr,
                           const bf16* residb, long ldrb,
                           int M, int N, int K, int relu, int relshift, int Z) {
        dim3 g((N + BN - 1) / BN, M / BM, Z);
        gemm_nt<<<g, 256, 0, stream>>>(A, lda, sAz, Bt, ldb, sBz,
                                       Cb, Cb2, ldc, sCz, bias, bias2,
                                       resid, ldr, residb, ldrb,
                                       M, N, K, relu, relshift);
    };

    // ---- input converts + weight transposes ----
    convert_f2b<<<dim3((unsigned)((ND + 255) / 256)), 256, 0, stream>>>(w, w_bf, ND);
    convert_f2b<<<dim3((unsigned)((ND + 255) / 256)), 256, 0, stream>>>(r, r_bf, ND);
    transpose_f2b<<<dim3(D / 32, D / 32), 256, 0, stream>>>(Wq, wqT, D, D);
    transpose_f2b<<<dim3(D / 32, D / 32), 256, 0, stream>>>(Wk, wkT, D, D);
    transpose_f2b<<<dim3(D / 32, D / 32), 256, 0, stream>>>(Wv, wvT, D, D);
    transpose_f2b<<<dim3(D / 32, D / 32), 256, 0, stream>>>(Wr, wrT, D, D);
    transpose_f2b<<<dim3(D / 32, D / 32), 256, 0, stream>>>(Wo, woT, D, D);
    transpose_f2b<<<dim3(DI / 32, D / 32), 256, 0, stream>>>(W1, w1T, D, DI);
    transpose_f2b<<<dim3(D / 32, DI / 32), 256, 0, stream>>>(W2, w2T, DI, D);

    // ---- projections ----
    launch_gemm(w_bf, D, 0, wqT, D, 0, Qw, Qr, D, 0,
                w_bias, r_bias, nullptr, 0, nullptr, 0, (int)MS, D, D, 0, 0, 1);
    launch_gemm(w_bf, D, 0, wkT, D, 0, Kb, nullptr, D, 0,
                nullptr, nullptr, nullptr, 0, nullptr, 0, (int)MS, D, D, 0, 0, 1);
    launch_gemm(w_bf, D, 0, wvT, D, 0, Vb, nullptr, D, 0,
                nullptr, nullptr, nullptr, 0, nullptr, 0, (int)MS, D, D, 0, 0, 1);
    launch_gemm(r_bf, D, 0, wrT, D, 0, RRb, nullptr, D, 0,
                nullptr, nullptr, nullptr, 0, nullptr, 0, (int)MS, D, D, 0, 0, 1);
    transpose_v<<<dim3(S / 32, DH / 32, B * NH), 256, 0, stream>>>(Vb, VT);

    // ---- attention (per-batch; SC reused via stream order; Vb clobbered after transpose) ----
    for (int b = 0; b < B; ++b) {
        const bf16* Qwb  = Qw  + (long)b * S * D;
        const bf16* Qrb  = Qr  + (long)b * S * D;
        const bf16* Kbb  = Kb  + (long)b * S * D;
        const bf16* RRbb = RRb + (long)b * S * D;
        // SC = (q + w_bias) @ K^T  per head
        launch_gemm(Qwb, D, DH, Kbb, D, DH, SC, nullptr, S, (long)S * S,
                    nullptr, nullptr, nullptr, 0, nullptr, 0, S, S, DH, 0, 0, NH);
        // SC[i, j+i-(S-1)] += (q + r_bias) @ RR^T  (rel-shift fused into epilogue)
        launch_gemm(Qrb, D, DH, RRbb, D, DH, SC, nullptr, S, (long)S * S,
                    nullptr, nullptr, nullptr, 0, nullptr, 0, S, S, DH, 0, 1, NH);
        softmax_rel<<<dim3(S, NH), 256, 0, stream>>>(SC, 0.125f);
        // attn_vec = P @ V  per head
        launch_gemm(SC, S, (long)S * S, VT + (long)b * NH * DH * S, S, (long)DH * S,
                    attn_vec + (long)b * S * D, nullptr, D, DH,
                    nullptr, nullptr, nullptr, 0, nullptr, 0, S, DH, S, 0, 0, NH);
    }

    // ---- output proj + residual, ln1, FFN, ln2 ----
    launch_gemm(attn_vec, D, 0, woT, D, 0, yb, nullptr, D, 0,
                nullptr, nullptr, w, D, nullptr, 0, (int)MS, D, D, 0, 0, 1);
    layernorm_b<<<dim3((unsigned)MS), 256, 0, stream>>>(yb, ln1_g, ln1_b, nullptr, x_bf);
    launch_gemm(x_bf, D, 0, w1T, D, 0, h, nullptr, DI, 0,
                b1, nullptr, nullptr, 0, nullptr, 0, (int)MS, DI, D, 1, 0, 1);
    launch_gemm(h, DI, 0, w2T, DI, 0, yb, nullptr, D, 0,
                b2, nullptr, nullptr, 0, x_bf, D, (int)MS, D, DI, 0, 0, 1);
    layernorm_b<<<dim3((unsigned)MS), 256, 0, stream>>>(yb, ln2_g, ln2_b, out, nullptr);
}

// Round 3
// 970.536 us; speedup vs baseline: 1.2168x; 1.2168x over previous
//
#include <hip/hip_runtime.h>
#include <hip/hip_bf16.h>

using bf16 = __hip_bfloat16;
typedef __attribute__((ext_vector_type(8))) short bf16x8;
typedef __attribute__((ext_vector_type(4))) float f32x4;

static constexpr int TB  = 4;
static constexpr int TS  = 1024;
static constexpr int TD  = 1024;
static constexpr int TNH = 16;
static constexpr int TDH = 64;
static constexpr int TDI = 4096;

enum { FRELU = 1, FRESF = 2, FRESB = 4, FSHIFT = 8, FQKV = 16 };

__device__ __forceinline__ void gll16(const bf16* g, bf16* l)
{
    __builtin_amdgcn_global_load_lds(
        (const __attribute__((address_space(1))) void*)g,
        (__attribute__((address_space(3))) void*)l, 16, 0, 0);
}

// ---------------- fallback: zero-fill output ----------------
__global__ __launch_bounds__(256) void zero_out_k(float* __restrict__ out, long n)
{
    long i = (long)blockIdx.x * 256 + threadIdx.x;
    if (i < n) out[i] = 0.0f;
}

// ---------------- fp32 -> bf16, 8 elems/thread, two tensors via grid.y ----------------
__global__ __launch_bounds__(256) void convert2_f2b(const float* __restrict__ a,
                                                    const float* __restrict__ b,
                                                    bf16* __restrict__ oa,
                                                    bf16* __restrict__ ob, long n)
{
    const float* src = blockIdx.y ? b : a;
    bf16* dst = blockIdx.y ? ob : oa;
    long i = ((long)blockIdx.x * 256 + threadIdx.x) * 8;
    if (i >= n) return;
    float4 f0 = *(const float4*)(src + i);
    float4 f1 = *(const float4*)(src + i + 4);
    bf16 t[8] = {__float2bfloat16(f0.x), __float2bfloat16(f0.y),
                 __float2bfloat16(f0.z), __float2bfloat16(f0.w),
                 __float2bfloat16(f1.x), __float2bfloat16(f1.y),
                 __float2bfloat16(f1.z), __float2bfloat16(f1.w)};
    *(bf16x8*)(dst + i) = *(bf16x8*)t;
}

// ---------------- transpose fp32 [R,C] -> bf16 [C,R] ----------------
__global__ __launch_bounds__(256) void transpose_f2b(const float* __restrict__ in,
                                                     bf16* __restrict__ out,
                                                     int R, int C)
{
    __shared__ float tile[32][33];
    int c0 = blockIdx.x * 32, r0 = blockIdx.y * 32;
    int tx = threadIdx.x & 31, ty = threadIdx.x >> 5;
#pragma unroll
    for (int dy = 0; dy < 32; dy += 8)
        tile[ty + dy][tx] = in[(long)(r0 + ty + dy) * C + (c0 + tx)];
    __syncthreads();
#pragma unroll
    for (int dy = 0; dy < 32; dy += 8)
        out[(long)(c0 + ty + dy) * R + (r0 + tx)] = __float2bfloat16(tile[tx][ty + dy]);
}

// ---------------- 5x square D x D transpose in one launch ----------------
__global__ __launch_bounds__(256) void transpose5_f2b(const float* __restrict__ p0,
                                                      const float* __restrict__ p1,
                                                      const float* __restrict__ p2,
                                                      const float* __restrict__ p3,
                                                      const float* __restrict__ p4,
                                                      bf16* __restrict__ dstBase)
{
    __shared__ float tile[32][33];
    const int D = TD;
    int z = blockIdx.z;
    const float* in = (z == 0) ? p0 : (z == 1) ? p1 : (z == 2) ? p2 : (z == 3) ? p3 : p4;
    bf16* out = dstBase + (long)z * D * D;
    int c0 = blockIdx.x * 32, r0 = blockIdx.y * 32;
    int tx = threadIdx.x & 31, ty = threadIdx.x >> 5;
#pragma unroll
    for (int dy = 0; dy < 32; dy += 8)
        tile[ty + dy][tx] = in[(long)(r0 + ty + dy) * D + (c0 + tx)];
    __syncthreads();
#pragma unroll
    for (int dy = 0; dy < 32; dy += 8)
        out[(long)(c0 + ty + dy) * D + (r0 + tx)] = __float2bfloat16(tile[tx][ty + dy]);
}

// ---------------- transpose V [B,S,NH*DH] bf16 -> VT [B,NH,DH,S] bf16 ----------------
__global__ __launch_bounds__(256) void transpose_v(const bf16* __restrict__ V,
                                                   bf16* __restrict__ VT)
{
    __shared__ bf16 tile[32][33];
    int bn = blockIdx.z;
    int b = bn >> 4, n = bn & 15;
    const bf16* src = V + ((long)b * TS) * (TNH * TDH) + n * TDH;
    bf16* dst = VT + (long)bn * TDH * TS;
    int s0 = blockIdx.x * 32, d0 = blockIdx.y * 32;
    int tx = threadIdx.x & 31, ty = threadIdx.x >> 5;
#pragma unroll
    for (int dy = 0; dy < 32; dy += 8)
        tile[ty + dy][tx] = src[(long)(s0 + ty + dy) * (TNH * TDH) + (d0 + tx)];
    __syncthreads();
#pragma unroll
    for (int dy = 0; dy < 32; dy += 8)
        dst[(long)(d0 + ty + dy) * TS + (s0 + tx)] = tile[tx][ty + dy];
}

// ---------------- m97-style NT bf16 MFMA GEMM ----------------
// C[M,N] = A[M,K] @ Bt[N,K]^T, all row-major bf16. 1D grid.x = GX*GY (column-major
// tile order: ty = l % GY for XCD-local A-tile reuse), grid.y = z batch.
// BNT: 128 (4 waves 2x2 of 64x64) or 64 (4 waves 2x2 of 64x32).
#define BM 128
#define BKK 32

template<int BNT>
__global__ __launch_bounds__(256) void gemm_k(
    const bf16* __restrict__ A, long lda, long sAz,
    const bf16* __restrict__ Bt, long ldb, long sBz,
    bf16* __restrict__ C0, bf16* __restrict__ C1,
    bf16* __restrict__ C2, bf16* __restrict__ C3,
    long ldc, long sCz,
    const float* __restrict__ bias, const float* __restrict__ bias2,
    const float* __restrict__ residf, const bf16* __restrict__ residb,
    int N, int K, int GY, int mode)
{
    constexpr int WNW = BNT / 2;    // per-wave N extent
    constexpr int FRJ = WNW / 16;   // B frags per wave
    constexpr int BCH = BNT / 64;   // B staging chunks per wave

    __shared__ bf16 As[BM * BKK];
    __shared__ bf16 Bs[BNT * BKK];

    const int z = blockIdx.y;
    A  += (long)z * sAz;
    Bt += (long)z * sBz;
    const long coff = (long)z * sCz;

    long l = blockIdx.x;
    const int ty = (int)(l % GY);
    const int tx = (int)(l / GY);
    const int row0 = ty * BM;
    const int col0 = tx * BNT;

    const int tid  = threadIdx.x;
    const int lane = tid & 63;
    const int wave = tid >> 6;
    const int wm = (wave & 1) * 64;
    const int wn = (wave >> 1) * WNW;
    const int lr = lane & 15;
    const int lk = (lane >> 4) << 3;

    // staging lane map: chunk = 16 rows x 32 cols (512 elems, 1 KB)
    const int sr  = lane >> 2;
    const int skc = (lane & 3) << 3;

    f32x4 acc[4][FRJ] = {};

    for (int k0 = 0; k0 < K; k0 += BKK) {
#pragma unroll
        for (int c = 0; c < 2; ++c) {
            int ch = wave * 2 + c;
            gll16(A + (long)(row0 + ch * 16 + sr) * lda + (k0 + skc), &As[ch * 512]);
        }
#pragma unroll
        for (int c = 0; c < BCH; ++c) {
            int ch = wave * BCH + c;
            gll16(Bt + (long)(col0 + ch * 16 + sr) * ldb + (k0 + skc), &Bs[ch * 512]);
        }
        __syncthreads();

        bf16x8 af[4], bfv[FRJ];
#pragma unroll
        for (int t = 0; t < 4; ++t)
            af[t] = *(const bf16x8*)(&As[(wm + t * 16 + lr) * BKK + lk]);
#pragma unroll
        for (int t = 0; t < FRJ; ++t)
            bfv[t] = *(const bf16x8*)(&Bs[(wn + t * 16 + lr) * BKK + lk]);
#pragma unroll
        for (int i = 0; i < 4; ++i)
#pragma unroll
            for (int j = 0; j < FRJ; ++j)
                acc[i][j] = __builtin_amdgcn_mfma_f32_16x16x32_bf16(
                    af[i], bfv[j], acc[i][j], 0, 0, 0);
        __syncthreads();
    }

    const int lq = (lane >> 4) << 2;
#pragma unroll
    for (int i = 0; i < 4; ++i) {
#pragma unroll
        for (int j = 0; j < FRJ; ++j) {
#pragma unroll
            for (int rg = 0; rg < 4; ++rg) {
                int mrow = row0 + wm + i * 16 + lq + rg;
                int ncol = col0 + wn + j * 16 + lr;
                float v = acc[i][j][rg];
                long rbase = (long)mrow * ldc;
                if (mode & FQKV) {
                    if (ncol < 1024) {
                        C0[rbase + ncol] = __float2bfloat16(v + bias[ncol]);
                        C1[rbase + ncol] = __float2bfloat16(v + bias2[ncol]);
                    } else if (ncol < 2048) {
                        C2[rbase + ncol - 1024] = __float2bfloat16(v);
                    } else {
                        C3[rbase + ncol - 2048] = __float2bfloat16(v);
                    }
                    continue;
                }
                if (bias)          v += bias[ncol];
                if (mode & FRELU)  v = fmaxf(v, 0.0f);
                if (mode & FRESF)  v += residf[rbase + ncol];
                if (mode & FRESB)  v += __bfloat162float(residb[rbase + ncol]);
                long cidx;
                if (mode & FSHIFT) {
                    int c = ncol + mrow - (N - 1);
                    if (c < 0) continue;
                    cidx = coff + rbase + c;
                    v += __bfloat162float(C0[cidx]);
                } else {
                    cidx = coff + rbase + ncol;
                }
                C0[cidx] = __float2bfloat16(v);
            }
        }
    }
}

// ---------------- causal softmax, in-place bf16 ----------------
__global__ __launch_bounds__(256) void softmax_rel(bf16* __restrict__ SC, float scale)
{
    const int S = TS;
    int i = blockIdx.x, n = blockIdx.y;
    long rowoff = ((long)n * S + i) * S;
    bf16* p = SC + rowoff;
    int tid = threadIdx.x;
    int L = i + 1;
    int wave = tid >> 6;

    float sv[4];
    float mx = -1e30f;
#pragma unroll
    for (int it = 0; it < 4; ++it) {
        int j = tid + it * 256;
        float s = -1e30f;
        if (j < L) s = __bfloat162float(p[j]) * scale;
        sv[it] = s;
        mx = fmaxf(mx, s);
    }
    for (int off = 32; off; off >>= 1) mx = fmaxf(mx, __shfl_xor(mx, off));
    __shared__ float sm[4];
    if ((tid & 63) == 0) sm[wave] = mx;
    __syncthreads();
    mx = fmaxf(fmaxf(sm[0], sm[1]), fmaxf(sm[2], sm[3]));

    float e[4];
    float sum = 0.0f;
#pragma unroll
    for (int it = 0; it < 4; ++it) {
        int j = tid + it * 256;
        float ev = (j < L) ? expf(sv[it] - mx) : 0.0f;
        e[it] = ev;
        sum += ev;
    }
    for (int off = 32; off; off >>= 1) sum += __shfl_xor(sum, off);
    __shared__ float ss[4];
    if ((tid & 63) == 0) ss[wave] = sum;
    __syncthreads();
    sum = ss[0] + ss[1] + ss[2] + ss[3];
    float inv = 1.0f / sum;
#pragma unroll
    for (int it = 0; it < 4; ++it) {
        int j = tid + it * 256;
        p[j] = __float2bfloat16(e[it] * inv);
    }
}

// ---------------- LayerNorm over D=1024, bf16 in, fp32 and/or bf16 out ----------------
__global__ __launch_bounds__(256) void layernorm_b(const bf16* __restrict__ X,
                                                   const float* __restrict__ g,
                                                   const float* __restrict__ bta,
                                                   float* __restrict__ Yf,
                                                   bf16* __restrict__ Yb)
{
    const int D = TD;
    long row = blockIdx.x;
    const bf16* x = X + row * D;
    int tid = threadIdx.x;
    int wave = tid >> 6;

    float v[4], s = 0.0f;
#pragma unroll
    for (int it = 0; it < 4; ++it) { v[it] = __bfloat162float(x[tid + it * 256]); s += v[it]; }
    for (int off = 32; off; off >>= 1) s += __shfl_xor(s, off);
    __shared__ float sm[8];
    if ((tid & 63) == 0) sm[wave] = s;
    __syncthreads();
    float mean = (sm[0] + sm[1] + sm[2] + sm[3]) * (1.0f / D);

    float var = 0.0f;
#pragma unroll
    for (int it = 0; it < 4; ++it) { float d = v[it] - mean; var += d * d; }
    for (int off = 32; off; off >>= 1) var += __shfl_xor(var, off);
    if ((tid & 63) == 0) sm[4 + wave] = var;
    __syncthreads();
    var = (sm[4] + sm[5] + sm[6] + sm[7]) * (1.0f / D);
    float rinv = rsqrtf(var + 1e-5f);

#pragma unroll
    for (int it = 0; it < 4; ++it) {
        int c = tid + it * 256;
        float o = (v[it] - mean) * rinv * g[c] + bta[c];
        if (Yf) Yf[row * D + c] = o;
        if (Yb) Yb[row * D + c] = __float2bfloat16(o);
    }
}

extern "C" void kernel_launch(void* const* d_in, const int* in_sizes, int n_in,
                              void* d_out, int out_size, void* d_ws, size_t ws_size,
                              hipStream_t stream)
{
    const float* w      = (const float*)d_in[0];
    const float* r      = (const float*)d_in[1];
    const float* w_bias = (const float*)d_in[2];
    const float* r_bias = (const float*)d_in[3];
    const float* Wq     = (const float*)d_in[4];
    const float* Wk     = (const float*)d_in[5];
    const float* Wv     = (const float*)d_in[6];
    const float* Wr     = (const float*)d_in[7];
    const float* Wo     = (const float*)d_in[8];
    const float* ln1_g  = (const float*)d_in[9];
    const float* ln1_b  = (const float*)d_in[10];
    const float* W1     = (const float*)d_in[11];
    const float* b1     = (const float*)d_in[12];
    const float* W2     = (const float*)d_in[13];
    const float* b2     = (const float*)d_in[14];
    const float* ln2_g  = (const float*)d_in[15];
    const float* ln2_b  = (const float*)d_in[16];
    float* out = (float*)d_out;

    const int  B = TB, S = TS, D = TD, NH = TNH, DH = TDH, DI = TDI;
    const long MS = (long)B * S;            // 4096
    const long ND = (long)MS * D;           // 4M elems

    char* base = (char*)d_ws;
    size_t off = 0;
    auto alloc = [&](size_t bytes) -> void* {
        void* p = base + off;
        off += (bytes + 255) & ~(size_t)255;
        return p;
    };
    bf16* wqT  = (bf16*)alloc(2UL * D * D);   // contiguous: wqT..wvT form QKV B
    bf16* wkT  = (bf16*)alloc(2UL * D * D);
    bf16* wvT  = (bf16*)alloc(2UL * D * D);
    bf16* wrT  = (bf16*)alloc(2UL * D * D);
    bf16* woT  = (bf16*)alloc(2UL * D * D);
    bf16* w1T  = (bf16*)alloc(2UL * D * DI);
    bf16* w2T  = (bf16*)alloc(2UL * DI * D);
    bf16* bufA = (bf16*)alloc(2UL * ND);            // w_bf, later attn_vec
    bf16* bufB = (bf16*)alloc(2UL * ND);            // r_bf, later x_bf
    bf16* Qw   = (bf16*)alloc(2UL * ND);
    bf16* Qr   = (bf16*)alloc(2UL * ND);
    bf16* Kb   = (bf16*)alloc(2UL * ND);
    bf16* RRb  = (bf16*)alloc(2UL * ND);
    bf16* VT   = (bf16*)alloc(2UL * ND);
    bf16* R0   = (bf16*)alloc(2UL * NH * S * S);    // Vb -> SC -> h (32 MB)
    bf16* yb   = (bf16*)alloc(2UL * ND);
    size_t need = off;
    (void)in_sizes; (void)n_in; (void)out_size;

    if (ws_size < need) {
        zero_out_k<<<dim3((unsigned)((ND + 255) / 256)), 256, 0, stream>>>(out, ND);
        return;
    }

    bf16* w_bf = bufA;  bf16* attn_vec = bufA;
    bf16* r_bf = bufB;  bf16* x_bf     = bufB;
    bf16* Vb   = R0;    bf16* SC       = R0;    bf16* h = R0;

    auto gemm128 = [&](const bf16* A, long lda, long sAz,
                       const bf16* Bt, long ldb, long sBz,
                       bf16* C0, bf16* C1, bf16* C2, bf16* C3, long ldc, long sCz,
                       const float* bias, const float* bias2,
                       const float* rf, const bf16* rb,
                       int M, int N, int K, int mode, int Z) {
        int GY = M / BM, GX = N / 128;
        gemm_k<128><<<dim3((unsigned)(GX * GY), Z), 256, 0, stream>>>(
            A, lda, sAz, Bt, ldb, sBz, C0, C1, C2, C3, ldc, sCz,
            bias, bias2, rf, rb, N, K, GY, mode);
    };
    auto gemm64 = [&](const bf16* A, long lda, long sAz,
                      const bf16* Bt, long ldb, long sBz,
                      bf16* C0, long ldc, long sCz,
                      int M, int N, int K, int mode, int Z) {
        int GY = M / BM, GX = N / 64;
        gemm_k<64><<<dim3((unsigned)(GX * GY), Z), 256, 0, stream>>>(
            A, lda, sAz, Bt, ldb, sBz, C0, nullptr, nullptr, nullptr, ldc, sCz,
            nullptr, nullptr, nullptr, nullptr, N, K, GY, mode);
    };

    // ---- converts + weight transposes ----
    convert2_f2b<<<dim3((unsigned)(ND / (8 * 256)), 2), 256, 0, stream>>>(
        w, r, w_bf, r_bf, ND);
    transpose5_f2b<<<dim3(D / 32, D / 32, 5), 256, 0, stream>>>(
        Wq, Wk, Wv, Wr, Wo, wqT);
    transpose_f2b<<<dim3(DI / 32, D / 32), 256, 0, stream>>>(W1, w1T, D, DI);
    transpose_f2b<<<dim3(D / 32, DI / 32), 256, 0, stream>>>(W2, w2T, DI, D);

    // ---- fused QKV projection: B = [wqT; wkT; wvT] (N=3072) ----
    gemm128(w_bf, D, 0, wqT, D, 0, Qw, Qr, Kb, Vb, D, 0,
            w_bias, r_bias, nullptr, nullptr, (int)MS, 3 * D, D, FQKV, 1);
    // ---- R projection ----
    gemm128(r_bf, D, 0, wrT, D, 0, RRb, nullptr, nullptr, nullptr, D, 0,
            nullptr, nullptr, nullptr, nullptr, (int)MS, D, D, 0, 1);
    transpose_v<<<dim3(S / 32, DH / 32, B * NH), 256, 0, stream>>>(Vb, VT);

    // ---- attention (per-batch; SC reused via stream order) ----
    for (int b = 0; b < B; ++b) {
        const bf16* Qwb  = Qw  + (long)b * S * D;
        const bf16* Qrb  = Qr  + (long)b * S * D;
        const bf16* Kbb  = Kb  + (long)b * S * D;
        const bf16* RRbb = RRb + (long)b * S * D;
        gemm128(Qwb, D, DH, Kbb, D, DH, SC, nullptr, nullptr, nullptr, S, (long)S * S,
                nullptr, nullptr, nullptr, nullptr, S, S, DH, 0, NH);
        gemm128(Qrb, D, DH, RRbb, D, DH, SC, nullptr, nullptr, nullptr, S, (long)S * S,
                nullptr, nullptr, nullptr, nullptr, S, S, DH, FSHIFT, NH);
        softmax_rel<<<dim3(S, NH), 256, 0, stream>>>(SC, 0.125f);
        gemm64(SC, S, (long)S * S, VT + (long)b * NH * DH * S, S, (long)DH * S,
               attn_vec + (long)b * S * D, D, DH, S, DH, S, 0, NH);
    }

    // ---- output proj + residual, ln1, FFN, ln2 ----
    gemm128(attn_vec, D, 0, woT, D, 0, yb, nullptr, nullptr, nullptr, D, 0,
            nullptr, nullptr, w, nullptr, (int)MS, D, D, FRESF, 1);
    layernorm_b<<<dim3((unsigned)MS), 256, 0, stream>>>(yb, ln1_g, ln1_b, nullptr, x_bf);
    gemm128(x_bf, D, 0, w1T, D, 0, h, nullptr, nullptr, nullptr, DI, 0,
            b1, nullptr, nullptr, nullptr, (int)MS, DI, D, FRELU, 1);
    gemm128(h, DI, 0, w2T, DI, 0, yb, nullptr, nullptr, nullptr, D, 0,
            b2, nullptr, nullptr, x_bf, (int)MS, D, DI, FRESB, 1);
    layernorm_b<<<dim3((unsigned)MS), 256, 0, stream>>>(yb, ln2_g, ln2_b, out, nullptr);
}

// Round 4
// 514.520 us; speedup vs baseline: 2.2952x; 1.8863x over previous
//
#include <hip/hip_runtime.h>
#include <hip/hip_bf16.h>

using bf16 = __hip_bfloat16;
typedef __attribute__((ext_vector_type(8))) short bf16x8;
typedef __attribute__((ext_vector_type(4))) float f32x4;

static constexpr int TB  = 4;
static constexpr int TS  = 1024;
static constexpr int TD  = 1024;
static constexpr int TNH = 16;
static constexpr int TDH = 64;
static constexpr int TDI = 4096;

enum { FRELU = 1, FRESF = 2, FRESB = 4, FQKV = 16 };

__device__ __forceinline__ void gll16(const bf16* g, bf16* l)
{
    __builtin_amdgcn_global_load_lds(
        (const __attribute__((address_space(1))) void*)g,
        (__attribute__((address_space(3))) void*)l, 16, 0, 0);
}

// ---------------- fallback ----------------
__global__ __launch_bounds__(256) void zero_out_k(float* __restrict__ out, long n)
{
    long i = (long)blockIdx.x * 256 + threadIdx.x;
    if (i < n) out[i] = 0.0f;
}

// ---------------- fp32 -> bf16, 8/thread, two tensors ----------------
__global__ __launch_bounds__(256) void convert2_f2b(const float* __restrict__ a,
                                                    const float* __restrict__ b,
                                                    bf16* __restrict__ oa,
                                                    bf16* __restrict__ ob, long n)
{
    const float* src = blockIdx.y ? b : a;
    bf16* dst = blockIdx.y ? ob : oa;
    long i = ((long)blockIdx.x * 256 + threadIdx.x) * 8;
    if (i >= n) return;
    float4 f0 = *(const float4*)(src + i);
    float4 f1 = *(const float4*)(src + i + 4);
    bf16 t[8] = {__float2bfloat16(f0.x), __float2bfloat16(f0.y),
                 __float2bfloat16(f0.z), __float2bfloat16(f0.w),
                 __float2bfloat16(f1.x), __float2bfloat16(f1.y),
                 __float2bfloat16(f1.z), __float2bfloat16(f1.w)};
    *(bf16x8*)(dst + i) = *(bf16x8*)t;
}

// ---------------- transpose fp32 [R,C] -> bf16 [C,R] ----------------
__global__ __launch_bounds__(256) void transpose_f2b(const float* __restrict__ in,
                                                     bf16* __restrict__ out,
                                                     int R, int C)
{
    __shared__ float tile[32][33];
    int c0 = blockIdx.x * 32, r0 = blockIdx.y * 32;
    int tx = threadIdx.x & 31, ty = threadIdx.x >> 5;
#pragma unroll
    for (int dy = 0; dy < 32; dy += 8)
        tile[ty + dy][tx] = in[(long)(r0 + ty + dy) * C + (c0 + tx)];
    __syncthreads();
#pragma unroll
    for (int dy = 0; dy < 32; dy += 8)
        out[(long)(c0 + ty + dy) * R + (r0 + tx)] = __float2bfloat16(tile[tx][ty + dy]);
}

// ---------------- 5x square D x D transpose ----------------
__global__ __launch_bounds__(256) void transpose5_f2b(const float* __restrict__ p0,
                                                      const float* __restrict__ p1,
                                                      const float* __restrict__ p2,
                                                      const float* __restrict__ p3,
                                                      const float* __restrict__ p4,
                                                      bf16* __restrict__ dstBase)
{
    __shared__ float tile[32][33];
    const int D = TD;
    int z = blockIdx.z;
    const float* in = (z == 0) ? p0 : (z == 1) ? p1 : (z == 2) ? p2 : (z == 3) ? p3 : p4;
    bf16* out = dstBase + (long)z * D * D;
    int c0 = blockIdx.x * 32, r0 = blockIdx.y * 32;
    int tx = threadIdx.x & 31, ty = threadIdx.x >> 5;
#pragma unroll
    for (int dy = 0; dy < 32; dy += 8)
        tile[ty + dy][tx] = in[(long)(r0 + ty + dy) * D + (c0 + tx)];
    __syncthreads();
#pragma unroll
    for (int dy = 0; dy < 32; dy += 8)
        out[(long)(c0 + ty + dy) * D + (r0 + tx)] = __float2bfloat16(tile[tx][ty + dy]);
}

// ---------------- transpose V [B,S,NH*DH] -> VT [B,NH,DH,S] ----------------
__global__ __launch_bounds__(256) void transpose_v(const bf16* __restrict__ V,
                                                   bf16* __restrict__ VT)
{
    __shared__ bf16 tile[32][33];
    int bn = blockIdx.z;
    int b = bn >> 4, n = bn & 15;
    const bf16* src = V + ((long)b * TS) * (TNH * TDH) + n * TDH;
    bf16* dst = VT + (long)bn * TDH * TS;
    int s0 = blockIdx.x * 32, d0 = blockIdx.y * 32;
    int tx = threadIdx.x & 31, ty = threadIdx.x >> 5;
#pragma unroll
    for (int dy = 0; dy < 32; dy += 8)
        tile[ty + dy][tx] = src[(long)(s0 + ty + dy) * (TNH * TDH) + (d0 + tx)];
    __syncthreads();
#pragma unroll
    for (int dy = 0; dy < 32; dy += 8)
        dst[(long)(d0 + ty + dy) * TS + (s0 + tx)] = tile[tx][ty + dy];
}

// ---------------- m97-style NT bf16 MFMA GEMM ----------------
#define BM 128
#define BKK 32

template<int BNT>
__global__ __launch_bounds__(256) void gemm_k(
    const bf16* __restrict__ A, long lda, long sAz,
    const bf16* __restrict__ Bt, long ldb, long sBz,
    bf16* __restrict__ C0, bf16* __restrict__ C2, bf16* __restrict__ C3,
    long ldc, long sCz,
    const float* __restrict__ bias,
    const float* __restrict__ residf, const bf16* __restrict__ residb,
    int N, int K, int GY, int mode)
{
    constexpr int WNW = BNT / 2;
    constexpr int FRJ = WNW / 16;
    constexpr int BCH = BNT / 64;

    __shared__ bf16 As[BM * BKK];
    __shared__ bf16 Bs[BNT * BKK];

    const int z = blockIdx.y;
    A  += (long)z * sAz;
    Bt += (long)z * sBz;
    const long coff = (long)z * sCz;

    long l = blockIdx.x;
    const int ty = (int)(l % GY);
    const int tx = (int)(l / GY);
    const int row0 = ty * BM;
    const int col0 = tx * BNT;

    const int tid  = threadIdx.x;
    const int lane = tid & 63;
    const int wave = tid >> 6;
    const int wm = (wave & 1) * 64;
    const int wn = (wave >> 1) * WNW;
    const int lr = lane & 15;
    const int lk = (lane >> 4) << 3;

    const int sr  = lane >> 2;
    const int skc = (lane & 3) << 3;

    f32x4 acc[4][FRJ] = {};

    for (int k0 = 0; k0 < K; k0 += BKK) {
#pragma unroll
        for (int c = 0; c < 2; ++c) {
            int ch = wave * 2 + c;
            gll16(A + (long)(row0 + ch * 16 + sr) * lda + (k0 + skc), &As[ch * 512]);
        }
#pragma unroll
        for (int c = 0; c < BCH; ++c) {
            int ch = wave * BCH + c;
            gll16(Bt + (long)(col0 + ch * 16 + sr) * ldb + (k0 + skc), &Bs[ch * 512]);
        }
        __syncthreads();

        bf16x8 af[4], bfv[FRJ];
#pragma unroll
        for (int t = 0; t < 4; ++t)
            af[t] = *(const bf16x8*)(&As[(wm + t * 16 + lr) * BKK + lk]);
#pragma unroll
        for (int t = 0; t < FRJ; ++t)
            bfv[t] = *(const bf16x8*)(&Bs[(wn + t * 16 + lr) * BKK + lk]);
#pragma unroll
        for (int i = 0; i < 4; ++i)
#pragma unroll
            for (int j = 0; j < FRJ; ++j)
                acc[i][j] = __builtin_amdgcn_mfma_f32_16x16x32_bf16(
                    af[i], bfv[j], acc[i][j], 0, 0, 0);
        __syncthreads();
    }

    const int lq = (lane >> 4) << 2;
#pragma unroll
    for (int i = 0; i < 4; ++i) {
#pragma unroll
        for (int j = 0; j < FRJ; ++j) {
#pragma unroll
            for (int rg = 0; rg < 4; ++rg) {
                int mrow = row0 + wm + i * 16 + lq + rg;
                int ncol = col0 + wn + j * 16 + lr;
                float v = acc[i][j][rg];
                long rbase = (long)mrow * ldc;
                if (mode & FQKV) {
                    if (ncol < 1024) {
                        C0[rbase + ncol] = __float2bfloat16(v + bias[ncol]);
                    } else if (ncol < 2048) {
                        C2[rbase + ncol - 1024] = __float2bfloat16(v);
                    } else {
                        C3[rbase + ncol - 2048] = __float2bfloat16(v);
                    }
                    continue;
                }
                if (bias)          v += bias[ncol];
                if (mode & FRELU)  v = fmaxf(v, 0.0f);
                if (mode & FRESF)  v += residf[rbase + ncol];
                if (mode & FRESB)  v += __bfloat162float(residb[rbase + ncol]);
                C0[coff + rbase + ncol] = __float2bfloat16(v);
            }
        }
    }
}

// ---------------- fused flash attention with Transformer-XL rel-shift ----------------
// Grid: 512 blocks = (i_rev * 64 + b*16 + n). Block: 256 thr, 4 waves, 128 q-rows,
// each wave owns 32 exclusive q-rows. Iterates causal j-tiles of 128.
// score(i,j) = ( Qw_i·K_j + Qr_i·RR_{S-1+j-i} ) * 0.125, Qr = Qw + (r_bias - w_bias).
__global__ __launch_bounds__(256, 1) void flash_attn(
    const bf16* __restrict__ Qw, const bf16* __restrict__ Kb,
    const bf16* __restrict__ RRb, const bf16* __restrict__ VT,
    const float* __restrict__ wbias, const float* __restrict__ rbias,
    bf16* __restrict__ Oa)
{
    const int S = TS, D = TD;
    __shared__ bf16 Ks[128 * 64];        // swizzled cb^(row&7)
    __shared__ bf16 RRs[256 * 64];       // swizzled cb^(row&7)
    __shared__ bf16 VTs[64 * 128];       // swizzled cb^(row&15)
    __shared__ bf16 SCR[4][32 * 161];    // per-wave: BD band (stride 161) / P (stride 136)

    const int bx = blockIdx.x;
    const int irev = bx >> 6, bn = bx & 63;
    const int it = 7 - irev;
    const int i0 = it * 128;
    const int b = bn >> 4, n = bn & 15;

    const int tid = threadIdx.x, lane = tid & 63, wave = tid >> 6;
    const int dw = wave * 32;
    const int l15 = lane & 15, lq = lane >> 4;
    const int sr8 = lane >> 3, sc8 = lane & 7;     // K/RR staging: 8 rows x 64 cols
    const int vr4 = lane >> 4, vc16 = lane & 15;   // VT staging: 4 rows x 128 cols

    // ---- loop-invariant Q fragments (A-operand layout: row=l15, k=lq*8+jj) ----
    bf16x8 afw[2][2], afr[2][2];
#pragma unroll
    for (int m = 0; m < 2; ++m)
#pragma unroll
        for (int ks = 0; ks < 2; ++ks) {
            const bf16* qp = Qw + ((long)(b * S + i0 + dw + 16 * m + l15)) * D
                             + n * 64 + ks * 32 + lq * 8;
            afw[m][ks] = *(const bf16x8*)qp;
            bf16 tmp[8];
#pragma unroll
            for (int jj = 0; jj < 8; ++jj) {
                int di_ = n * 64 + ks * 32 + lq * 8 + jj;
                float f = __bfloat162float(((const bf16*)&afw[m][ks])[jj])
                          + rbias[di_] - wbias[di_];
                tmp[jj] = __float2bfloat16(f);
            }
            afr[m][ks] = *(bf16x8*)tmp;
        }

    float mst[2][4], lst[2][4];
    f32x4 Oacc[2][4] = {};
#pragma unroll
    for (int m = 0; m < 2; ++m)
#pragma unroll
        for (int rg = 0; rg < 4; ++rg) { mst[m][rg] = -1e30f; lst[m][rg] = 0.0f; }

    bf16* scr = &SCR[wave][0];
    const int cofs = 96 - dw;           // wave's BD band start (local c-offset)

    for (int jt = 0; jt <= it; ++jt) {
        const int j0 = jt * 128;
        const int cT0 = S - 1 + j0 - i0 - 127;   // global rr row of band offset 0 (>=0)

        // ---- stage K (16 chunks), RR band (32 chunks), VT (16 chunks) ----
#pragma unroll
        for (int c = 0; c < 4; ++c) {
            int ch = wave * 4 + c;
            int row = ch * 8 + sr8;
            int cbs = sc8 ^ (sr8 & 7);
            gll16(Kb + ((long)(b * S + j0 + row)) * D + n * 64 + cbs * 8, &Ks[ch * 512]);
        }
#pragma unroll
        for (int c = 0; c < 8; ++c) {
            int ch = wave * 8 + c;
            int row = ch * 8 + sr8;
            int grow = cT0 + row; if (grow > S - 1) grow = S - 1;  // feeds masked elems only
            int cbs = sc8 ^ (sr8 & 7);
            gll16(RRb + ((long)(b * S + grow)) * D + n * 64 + cbs * 8, &RRs[ch * 512]);
        }
#pragma unroll
        for (int c = 0; c < 4; ++c) {
            int ch = wave * 4 + c;
            int row = ch * 4 + vr4;                   // d in [0,64)
            int cbs = vc16 ^ (row & 15);
            gll16(VT + ((long)(bn * 64 + row)) * S + j0 + cbs * 8, &VTs[ch * 512]);
        }
        __syncthreads();

        // ---- BD band: bd[m][nf] over 160 band-cols ----
        f32x4 bd[2][10] = {};
#pragma unroll
        for (int ks = 0; ks < 2; ++ks) {
            bf16x8 bfr[10];
#pragma unroll
            for (int nf = 0; nf < 10; ++nf) {
                int row = cofs + nf * 16 + l15;
                int cb = ks * 4 + lq;
                bfr[nf] = *(const bf16x8*)(&RRs[row * 64 + (cb ^ (row & 7)) * 8]);
            }
#pragma unroll
            for (int m = 0; m < 2; ++m)
#pragma unroll
                for (int nf = 0; nf < 10; ++nf)
                    bd[m][nf] = __builtin_amdgcn_mfma_f32_16x16x32_bf16(
                        afr[m][ks], bfr[nf], bd[m][nf], 0, 0, 0);
        }
        // write band to per-wave scratch (stride 161)
#pragma unroll
        for (int m = 0; m < 2; ++m)
#pragma unroll
            for (int nf = 0; nf < 10; ++nf)
#pragma unroll
                for (int rg = 0; rg < 4; ++rg) {
                    int ldi = lq * 4 + rg + 16 * m;
                    scr[ldi * 161 + nf * 16 + l15] = __float2bfloat16(bd[m][nf][rg]);
                }

        // ---- AC ----
        f32x4 ac[2][8] = {};
#pragma unroll
        for (int ks = 0; ks < 2; ++ks) {
            bf16x8 bk[8];
#pragma unroll
            for (int nf = 0; nf < 8; ++nf) {
                int row = nf * 16 + l15;
                int cb = ks * 4 + lq;
                bk[nf] = *(const bf16x8*)(&Ks[row * 64 + (cb ^ (row & 7)) * 8]);
            }
#pragma unroll
            for (int m = 0; m < 2; ++m)
#pragma unroll
                for (int nf = 0; nf < 8; ++nf)
                    ac[m][nf] = __builtin_amdgcn_mfma_f32_16x16x32_bf16(
                        afw[m][ks], bk[nf], ac[m][nf], 0, 0, 0);
        }

        // ---- shift-add + mask + scale ----
        const bool diag = (jt == it);
#pragma unroll
        for (int m = 0; m < 2; ++m)
#pragma unroll
            for (int nf = 0; nf < 8; ++nf)
#pragma unroll
                for (int rg = 0; rg < 4; ++rg) {
                    int ldi = lq * 4 + rg + 16 * m;
                    int col = nf * 16 + l15;                 // dj
                    float bdv = __bfloat162float(scr[ldi * 161 + (col + 31 - ldi)]);
                    float s = (ac[m][nf][rg] + bdv) * 0.125f;
                    if (diag && (col > dw + ldi)) s = -1e30f;   // j0==i0 on diagonal
                    ac[m][nf][rg] = s;
                }

        // ---- online softmax ----
        float alpha[2][4];
#pragma unroll
        for (int m = 0; m < 2; ++m)
#pragma unroll
            for (int rg = 0; rg < 4; ++rg) {
                float v = -1e30f;
#pragma unroll
                for (int nf = 0; nf < 8; ++nf) v = fmaxf(v, ac[m][nf][rg]);
                for (int o = 8; o; o >>= 1) v = fmaxf(v, __shfl_xor(v, o));
                float mn = fmaxf(mst[m][rg], v);
                alpha[m][rg] = __expf(mst[m][rg] - mn);
                mst[m][rg] = mn;
            }
#pragma unroll
        for (int m = 0; m < 2; ++m)
#pragma unroll
            for (int nf = 0; nf < 8; ++nf)
#pragma unroll
                for (int rg = 0; rg < 4; ++rg)
                    ac[m][nf][rg] = __expf(ac[m][nf][rg] - mst[m][rg]);
#pragma unroll
        for (int m = 0; m < 2; ++m)
#pragma unroll
            for (int rg = 0; rg < 4; ++rg) {
                float sv = 0.0f;
#pragma unroll
                for (int nf = 0; nf < 8; ++nf) sv += ac[m][nf][rg];
                for (int o = 8; o; o >>= 1) sv += __shfl_xor(sv, o);
                lst[m][rg] = lst[m][rg] * alpha[m][rg] + sv;
            }
#pragma unroll
        for (int m = 0; m < 2; ++m)
#pragma unroll
            for (int nf = 0; nf < 4; ++nf)
#pragma unroll
                for (int rg = 0; rg < 4; ++rg)
                    Oacc[m][nf][rg] *= alpha[m][rg];

        // ---- P -> per-wave scratch (stride 136), then PV MFMA ----
#pragma unroll
        for (int m = 0; m < 2; ++m)
#pragma unroll
            for (int nf = 0; nf < 8; ++nf)
#pragma unroll
                for (int rg = 0; rg < 4; ++rg) {
                    int ldi = lq * 4 + rg + 16 * m;
                    scr[ldi * 136 + nf * 16 + l15] = __float2bfloat16(ac[m][nf][rg]);
                }
#pragma unroll
        for (int ks2 = 0; ks2 < 4; ++ks2) {
            bf16x8 pa[2];
#pragma unroll
            for (int m = 0; m < 2; ++m)
                pa[m] = *(const bf16x8*)(&scr[(16 * m + l15) * 136 + ks2 * 32 + lq * 8]);
            bf16x8 vb[4];
#pragma unroll
            for (int nf = 0; nf < 4; ++nf) {
                int row = nf * 16 + l15;
                int cb = ks2 * 4 + lq;
                vb[nf] = *(const bf16x8*)(&VTs[row * 128 + (cb ^ (row & 15)) * 8]);
            }
#pragma unroll
            for (int m = 0; m < 2; ++m)
#pragma unroll
                for (int nf = 0; nf < 4; ++nf)
                    Oacc[m][nf] = __builtin_amdgcn_mfma_f32_16x16x32_bf16(
                        pa[m], vb[nf], Oacc[m][nf], 0, 0, 0);
        }
        __syncthreads();
    }

    // ---- epilogue: O /= l, store ----
#pragma unroll
    for (int m = 0; m < 2; ++m)
#pragma unroll
        for (int rg = 0; rg < 4; ++rg) {
            float inv = 1.0f / lst[m][rg];
#pragma unroll
            for (int nf = 0; nf < 4; ++nf) {
                int row = i0 + dw + lq * 4 + rg + 16 * m;
                int col = nf * 16 + l15;
                Oa[((long)(b * S + row)) * D + n * 64 + col] =
                    __float2bfloat16(Oacc[m][nf][rg] * inv);
            }
        }
}

// ---------------- LayerNorm over D=1024 ----------------
__global__ __launch_bounds__(256) void layernorm_b(const bf16* __restrict__ X,
                                                   const float* __restrict__ g,
                                                   const float* __restrict__ bta,
                                                   float* __restrict__ Yf,
                                                   bf16* __restrict__ Yb)
{
    const int D = TD;
    long row = blockIdx.x;
    const bf16* x = X + row * D;
    int tid = threadIdx.x;
    int wave = tid >> 6;

    float v[4], s = 0.0f;
#pragma unroll
    for (int it = 0; it < 4; ++it) { v[it] = __bfloat162float(x[tid + it * 256]); s += v[it]; }
    for (int off = 32; off; off >>= 1) s += __shfl_xor(s, off);
    __shared__ float sm[8];
    if ((tid & 63) == 0) sm[wave] = s;
    __syncthreads();
    float mean = (sm[0] + sm[1] + sm[2] + sm[3]) * (1.0f / D);

    float var = 0.0f;
#pragma unroll
    for (int it = 0; it < 4; ++it) { float d = v[it] - mean; var += d * d; }
    for (int off = 32; off; off >>= 1) var += __shfl_xor(var, off);
    if ((tid & 63) == 0) sm[4 + wave] = var;
    __syncthreads();
    var = (sm[4] + sm[5] + sm[6] + sm[7]) * (1.0f / D);
    float rinv = rsqrtf(var + 1e-5f);

#pragma unroll
    for (int it = 0; it < 4; ++it) {
        int c = tid + it * 256;
        float o = (v[it] - mean) * rinv * g[c] + bta[c];
        if (Yf) Yf[row * D + c] = o;
        if (Yb) Yb[row * D + c] = __float2bfloat16(o);
    }
}

extern "C" void kernel_launch(void* const* d_in, const int* in_sizes, int n_in,
                              void* d_out, int out_size, void* d_ws, size_t ws_size,
                              hipStream_t stream)
{
    const float* w      = (const float*)d_in[0];
    const float* r      = (const float*)d_in[1];
    const float* w_bias = (const float*)d_in[2];
    const float* r_bias = (const float*)d_in[3];
    const float* Wq     = (const float*)d_in[4];
    const float* Wk     = (const float*)d_in[5];
    const float* Wv     = (const float*)d_in[6];
    const float* Wr     = (const float*)d_in[7];
    const float* Wo     = (const float*)d_in[8];
    const float* ln1_g  = (const float*)d_in[9];
    const float* ln1_b  = (const float*)d_in[10];
    const float* W1     = (const float*)d_in[11];
    const float* b1     = (const float*)d_in[12];
    const float* W2     = (const float*)d_in[13];
    const float* b2     = (const float*)d_in[14];
    const float* ln2_g  = (const float*)d_in[15];
    const float* ln2_b  = (const float*)d_in[16];
    float* out = (float*)d_out;

    const int  B = TB, S = TS, D = TD, NH = TNH, DH = TDH, DI = TDI;
    const long MS = (long)B * S;
    const long ND = (long)MS * D;

    char* base = (char*)d_ws;
    size_t off = 0;
    auto alloc = [&](size_t bytes) -> void* {
        void* p = base + off;
        off += (bytes + 255) & ~(size_t)255;
        return p;
    };
    bf16* wqT  = (bf16*)alloc(2UL * D * D);   // wqT..wvT contiguous = fused QKV B
    bf16* wkT  = (bf16*)alloc(2UL * D * D);
    bf16* wvT  = (bf16*)alloc(2UL * D * D);
    bf16* wrT  = (bf16*)alloc(2UL * D * D);
    bf16* woT  = (bf16*)alloc(2UL * D * D);
    bf16* w1T  = (bf16*)alloc(2UL * D * DI);
    bf16* w2T  = (bf16*)alloc(2UL * DI * D);
    bf16* bufA = (bf16*)alloc(2UL * ND);            // w_bf -> attn_vec
    bf16* bufB = (bf16*)alloc(2UL * ND);            // r_bf -> x_bf
    bf16* Qw   = (bf16*)alloc(2UL * ND);
    bf16* Kb   = (bf16*)alloc(2UL * ND);
    bf16* RRb  = (bf16*)alloc(2UL * ND);
    bf16* VT   = (bf16*)alloc(2UL * ND);
    bf16* R0   = (bf16*)alloc(2UL * MS * DI);       // Vb -> h (32 MB)
    bf16* yb   = (bf16*)alloc(2UL * ND);
    size_t need = off;
    (void)in_sizes; (void)n_in; (void)out_size;

    if (ws_size < need) {
        zero_out_k<<<dim3((unsigned)((ND + 255) / 256)), 256, 0, stream>>>(out, ND);
        return;
    }

    bf16* w_bf = bufA;  bf16* attn_vec = bufA;
    bf16* r_bf = bufB;  bf16* x_bf     = bufB;
    bf16* Vb   = R0;    bf16* h        = R0;

    auto gemm128 = [&](const bf16* A, const bf16* Bt,
                       bf16* C0, bf16* C2, bf16* C3, long ldc,
                       const float* bias, const float* rf, const bf16* rb,
                       int M, int N, int K, int mode) {
        int GY = M / BM, GX = N / 128;
        gemm_k<128><<<dim3((unsigned)(GX * GY), 1), 256, 0, stream>>>(
            A, K, 0, Bt, K, 0, C0, C2, C3, ldc, 0, bias, rf, rb, N, K, GY, mode);
    };
    auto gemm64 = [&](const bf16* A, const bf16* Bt, bf16* C0, long ldc,
                      const float* bias, const float* rf, const bf16* rb,
                      int M, int N, int K, int mode) {
        int GY = M / BM, GX = N / 64;
        gemm_k<64><<<dim3((unsigned)(GX * GY), 1), 256, 0, stream>>>(
            A, K, 0, Bt, K, 0, C0, nullptr, nullptr, ldc, 0, bias, rf, rb, N, K, GY, mode);
    };

    // ---- converts + weight transposes ----
    convert2_f2b<<<dim3((unsigned)(ND / (8 * 256)), 2), 256, 0, stream>>>(
        w, r, w_bf, r_bf, ND);
    transpose5_f2b<<<dim3(D / 32, D / 32, 5), 256, 0, stream>>>(
        Wq, Wk, Wv, Wr, Wo, wqT);
    transpose_f2b<<<dim3(DI / 32, D / 32), 256, 0, stream>>>(W1, w1T, D, DI);
    transpose_f2b<<<dim3(D / 32, DI / 32), 256, 0, stream>>>(W2, w2T, DI, D);

    // ---- projections ----
    gemm128(w_bf, wqT, Qw, Kb, Vb, D, w_bias, nullptr, nullptr,
            (int)MS, 3 * D, D, FQKV);
    gemm64(r_bf, wrT, RRb, D, nullptr, nullptr, nullptr, (int)MS, D, D, 0);
    transpose_v<<<dim3(S / 32, DH / 32, B * NH), 256, 0, stream>>>(Vb, VT);

    // ---- fused flash attention (all batches/heads, one launch) ----
    flash_attn<<<dim3(512), 256, 0, stream>>>(Qw, Kb, RRb, VT, w_bias, r_bias, attn_vec);

    // ---- output proj + residual, ln1, FFN, ln2 ----
    gemm64(attn_vec, woT, yb, D, nullptr, w, nullptr, (int)MS, D, D, FRESF);
    layernorm_b<<<dim3((unsigned)MS), 256, 0, stream>>>(yb, ln1_g, ln1_b, nullptr, x_bf);
    gemm128(x_bf, w1T, h, nullptr, nullptr, DI, b1, nullptr, nullptr,
            (int)MS, DI, D, FRELU);
    gemm64(h, w2T, yb, D, b2, nullptr, x_bf, (int)MS, D, DI, FRESB);
    layernorm_b<<<dim3((unsigned)MS), 256, 0, stream>>>(yb, ln2_g, ln2_b, out, nullptr);
}

// Round 5
// 487.563 us; speedup vs baseline: 2.4221x; 1.0553x over previous
//
#include <hip/hip_runtime.h>
#include <hip/hip_bf16.h>

using bf16 = __hip_bfloat16;
typedef __attribute__((ext_vector_type(8))) short bf16x8;
typedef __attribute__((ext_vector_type(4))) float f32x4;

static constexpr int TB  = 4;
static constexpr int TS  = 1024;
static constexpr int TD  = 1024;
static constexpr int TNH = 16;
static constexpr int TDH = 64;
static constexpr int TDI = 4096;

enum { FRELU = 1, FRESF = 2, FRESB = 4, FQKV = 16, FP32S = 32 };

__device__ __forceinline__ void gll16(const bf16* g, bf16* l)
{
    __builtin_amdgcn_global_load_lds(
        (const __attribute__((address_space(1))) void*)g,
        (__attribute__((address_space(3))) void*)l, 16, 0, 0);
}

// ---------------- fallback ----------------
__global__ __launch_bounds__(256) void zero_out_k(float* __restrict__ out, long n)
{
    long i = (long)blockIdx.x * 256 + threadIdx.x;
    if (i < n) out[i] = 0.0f;
}

// ---------------- fp32 -> bf16, 8/thread, two tensors ----------------
__global__ __launch_bounds__(256) void convert2_f2b(const float* __restrict__ a,
                                                    const float* __restrict__ b,
                                                    bf16* __restrict__ oa,
                                                    bf16* __restrict__ ob, long n)
{
    const float* src = blockIdx.y ? b : a;
    bf16* dst = blockIdx.y ? ob : oa;
    long i = ((long)blockIdx.x * 256 + threadIdx.x) * 8;
    if (i >= n) return;
    float4 f0 = *(const float4*)(src + i);
    float4 f1 = *(const float4*)(src + i + 4);
    bf16 t[8] = {__float2bfloat16(f0.x), __float2bfloat16(f0.y),
                 __float2bfloat16(f0.z), __float2bfloat16(f0.w),
                 __float2bfloat16(f1.x), __float2bfloat16(f1.y),
                 __float2bfloat16(f1.z), __float2bfloat16(f1.w)};
    *(bf16x8*)(dst + i) = *(bf16x8*)t;
}

// ---------------- transpose fp32 [R,C] -> bf16 [C,R] ----------------
__global__ __launch_bounds__(256) void transpose_f2b(const float* __restrict__ in,
                                                     bf16* __restrict__ out,
                                                     int R, int C)
{
    __shared__ float tile[32][33];
    int c0 = blockIdx.x * 32, r0 = blockIdx.y * 32;
    int tx = threadIdx.x & 31, ty = threadIdx.x >> 5;
#pragma unroll
    for (int dy = 0; dy < 32; dy += 8)
        tile[ty + dy][tx] = in[(long)(r0 + ty + dy) * C + (c0 + tx)];
    __syncthreads();
#pragma unroll
    for (int dy = 0; dy < 32; dy += 8)
        out[(long)(c0 + ty + dy) * R + (r0 + tx)] = __float2bfloat16(tile[tx][ty + dy]);
}

// ---------------- 5x square D x D transpose ----------------
__global__ __launch_bounds__(256) void transpose5_f2b(const float* __restrict__ p0,
                                                      const float* __restrict__ p1,
                                                      const float* __restrict__ p2,
                                                      const float* __restrict__ p3,
                                                      const float* __restrict__ p4,
                                                      bf16* __restrict__ dstBase)
{
    __shared__ float tile[32][33];
    const int D = TD;
    int z = blockIdx.z;
    const float* in = (z == 0) ? p0 : (z == 1) ? p1 : (z == 2) ? p2 : (z == 3) ? p3 : p4;
    bf16* out = dstBase + (long)z * D * D;
    int c0 = blockIdx.x * 32, r0 = blockIdx.y * 32;
    int tx = threadIdx.x & 31, ty = threadIdx.x >> 5;
#pragma unroll
    for (int dy = 0; dy < 32; dy += 8)
        tile[ty + dy][tx] = in[(long)(r0 + ty + dy) * D + (c0 + tx)];
    __syncthreads();
#pragma unroll
    for (int dy = 0; dy < 32; dy += 8)
        out[(long)(c0 + ty + dy) * D + (r0 + tx)] = __float2bfloat16(tile[tx][ty + dy]);
}

// ---------------- transpose V [B,S,NH*DH] -> VT [B,NH,DH,S] ----------------
__global__ __launch_bounds__(256) void transpose_v(const bf16* __restrict__ V,
                                                   bf16* __restrict__ VT)
{
    __shared__ bf16 tile[32][33];
    int bn = blockIdx.z;
    int b = bn >> 4, n = bn & 15;
    const bf16* src = V + ((long)b * TS) * (TNH * TDH) + n * TDH;
    bf16* dst = VT + (long)bn * TDH * TS;
    int s0 = blockIdx.x * 32, d0 = blockIdx.y * 32;
    int tx = threadIdx.x & 31, ty = threadIdx.x >> 5;
#pragma unroll
    for (int dy = 0; dy < 32; dy += 8)
        tile[ty + dy][tx] = src[(long)(s0 + ty + dy) * (TNH * TDH) + (d0 + tx)];
    __syncthreads();
#pragma unroll
    for (int dy = 0; dy < 32; dy += 8)
        dst[(long)(d0 + ty + dy) * TS + (s0 + tx)] = tile[tx][ty + dy];
}

// ---------------- m97-style NT bf16 MFMA GEMM ----------------
// FP32S: grid.y = K-split index z; A/Bt advance z*sAz/sBz along K; fp32 partial
// written to Cfp[z*sCz + row*ldc + col] with no epilogue (reduced in layernorm_f).
#define BM 128
#define BKK 32

template<int BNT>
__global__ __launch_bounds__(256) void gemm_k(
    const bf16* __restrict__ A, long lda, long sAz,
    const bf16* __restrict__ Bt, long ldb, long sBz,
    bf16* __restrict__ C0, bf16* __restrict__ C2, bf16* __restrict__ C3,
    float* __restrict__ Cfp,
    long ldc, long sCz,
    const float* __restrict__ bias,
    const float* __restrict__ residf, const bf16* __restrict__ residb,
    int N, int K, int GY, int mode)
{
    constexpr int WNW = BNT / 2;
    constexpr int FRJ = WNW / 16;
    constexpr int BCH = BNT / 64;

    __shared__ bf16 As[BM * BKK];
    __shared__ bf16 Bs[BNT * BKK];

    const int z = blockIdx.y;
    A  += (long)z * sAz;
    Bt += (long)z * sBz;
    const long coff = (long)z * sCz;

    long l = blockIdx.x;
    const int ty = (int)(l % GY);
    const int tx = (int)(l / GY);
    const int row0 = ty * BM;
    const int col0 = tx * BNT;

    const int tid  = threadIdx.x;
    const int lane = tid & 63;
    const int wave = tid >> 6;
    const int wm = (wave & 1) * 64;
    const int wn = (wave >> 1) * WNW;
    const int lr = lane & 15;
    const int lk = (lane >> 4) << 3;

    const int sr  = lane >> 2;
    const int skc = (lane & 3) << 3;

    f32x4 acc[4][FRJ] = {};

    for (int k0 = 0; k0 < K; k0 += BKK) {
#pragma unroll
        for (int c = 0; c < 2; ++c) {
            int ch = wave * 2 + c;
            gll16(A + (long)(row0 + ch * 16 + sr) * lda + (k0 + skc), &As[ch * 512]);
        }
#pragma unroll
        for (int c = 0; c < BCH; ++c) {
            int ch = wave * BCH + c;
            gll16(Bt + (long)(col0 + ch * 16 + sr) * ldb + (k0 + skc), &Bs[ch * 512]);
        }
        __syncthreads();

        bf16x8 af[4], bfv[FRJ];
#pragma unroll
        for (int t = 0; t < 4; ++t)
            af[t] = *(const bf16x8*)(&As[(wm + t * 16 + lr) * BKK + lk]);
#pragma unroll
        for (int t = 0; t < FRJ; ++t)
            bfv[t] = *(const bf16x8*)(&Bs[(wn + t * 16 + lr) * BKK + lk]);
#pragma unroll
        for (int i = 0; i < 4; ++i)
#pragma unroll
            for (int j = 0; j < FRJ; ++j)
                acc[i][j] = __builtin_amdgcn_mfma_f32_16x16x32_bf16(
                    af[i], bfv[j], acc[i][j], 0, 0, 0);
        __syncthreads();
    }

    const int lq = (lane >> 4) << 2;
#pragma unroll
    for (int i = 0; i < 4; ++i) {
#pragma unroll
        for (int j = 0; j < FRJ; ++j) {
#pragma unroll
            for (int rg = 0; rg < 4; ++rg) {
                int mrow = row0 + wm + i * 16 + lq + rg;
                int ncol = col0 + wn + j * 16 + lr;
                float v = acc[i][j][rg];
                long rbase = (long)mrow * ldc;
                if (mode & FP32S) {
                    Cfp[coff + rbase + ncol] = v;
                    continue;
                }
                if (mode & FQKV) {
                    if (ncol < 1024) {
                        C0[rbase + ncol] = __float2bfloat16(v + bias[ncol]);
                    } else if (ncol < 2048) {
                        C2[rbase + ncol - 1024] = __float2bfloat16(v);
                    } else {
                        C3[rbase + ncol - 2048] = __float2bfloat16(v);
                    }
                    continue;
                }
                if (bias)          v += bias[ncol];
                if (mode & FRELU)  v = fmaxf(v, 0.0f);
                if (mode & FRESF)  v += residf[rbase + ncol];
                if (mode & FRESB)  v += __bfloat162float(residb[rbase + ncol]);
                C0[coff + rbase + ncol] = __float2bfloat16(v);
            }
        }
    }
}

// ---------------- fused flash attention with Transformer-XL rel-shift ----------------
__global__ __launch_bounds__(256, 1) void flash_attn(
    const bf16* __restrict__ Qw, const bf16* __restrict__ Kb,
    const bf16* __restrict__ RRb, const bf16* __restrict__ VT,
    const float* __restrict__ wbias, const float* __restrict__ rbias,
    bf16* __restrict__ Oa)
{
    const int S = TS, D = TD;
    __shared__ bf16 Ks[128 * 64];
    __shared__ bf16 RRs[256 * 64];
    __shared__ bf16 VTs[64 * 128];
    __shared__ bf16 SCR[4][32 * 161];

    const int bx = blockIdx.x;
    const int irev = bx >> 6, bn = bx & 63;
    const int it = 7 - irev;
    const int i0 = it * 128;
    const int b = bn >> 4, n = bn & 15;

    const int tid = threadIdx.x, lane = tid & 63, wave = tid >> 6;
    const int dw = wave * 32;
    const int l15 = lane & 15, lq = lane >> 4;
    const int sr8 = lane >> 3, sc8 = lane & 7;
    const int vr4 = lane >> 4, vc16 = lane & 15;

    bf16x8 afw[2][2], afr[2][2];
#pragma unroll
    for (int m = 0; m < 2; ++m)
#pragma unroll
        for (int ks = 0; ks < 2; ++ks) {
            const bf16* qp = Qw + ((long)(b * S + i0 + dw + 16 * m + l15)) * D
                             + n * 64 + ks * 32 + lq * 8;
            afw[m][ks] = *(const bf16x8*)qp;
            bf16 tmp[8];
#pragma unroll
            for (int jj = 0; jj < 8; ++jj) {
                int di_ = n * 64 + ks * 32 + lq * 8 + jj;
                float f = __bfloat162float(((const bf16*)&afw[m][ks])[jj])
                          + rbias[di_] - wbias[di_];
                tmp[jj] = __float2bfloat16(f);
            }
            afr[m][ks] = *(bf16x8*)tmp;
        }

    float mst[2][4], lst[2][4];
    f32x4 Oacc[2][4] = {};
#pragma unroll
    for (int m = 0; m < 2; ++m)
#pragma unroll
        for (int rg = 0; rg < 4; ++rg) { mst[m][rg] = -1e30f; lst[m][rg] = 0.0f; }

    bf16* scr = &SCR[wave][0];
    const int cofs = 96 - dw;

    for (int jt = 0; jt <= it; ++jt) {
        const int j0 = jt * 128;
        const int cT0 = S - 1 + j0 - i0 - 127;

#pragma unroll
        for (int c = 0; c < 4; ++c) {
            int ch = wave * 4 + c;
            int row = ch * 8 + sr8;
            int cbs = sc8 ^ (sr8 & 7);
            gll16(Kb + ((long)(b * S + j0 + row)) * D + n * 64 + cbs * 8, &Ks[ch * 512]);
        }
#pragma unroll
        for (int c = 0; c < 8; ++c) {
            int ch = wave * 8 + c;
            int row = ch * 8 + sr8;
            int grow = cT0 + row; if (grow > S - 1) grow = S - 1;
            int cbs = sc8 ^ (sr8 & 7);
            gll16(RRb + ((long)(b * S + grow)) * D + n * 64 + cbs * 8, &RRs[ch * 512]);
        }
#pragma unroll
        for (int c = 0; c < 4; ++c) {
            int ch = wave * 4 + c;
            int row = ch * 4 + vr4;
            int cbs = vc16 ^ (row & 15);
            gll16(VT + ((long)(bn * 64 + row)) * S + j0 + cbs * 8, &VTs[ch * 512]);
        }
        __syncthreads();

        f32x4 bd[2][10] = {};
#pragma unroll
        for (int ks = 0; ks < 2; ++ks) {
            bf16x8 bfr[10];
#pragma unroll
            for (int nf = 0; nf < 10; ++nf) {
                int row = cofs + nf * 16 + l15;
                int cb = ks * 4 + lq;
                bfr[nf] = *(const bf16x8*)(&RRs[row * 64 + (cb ^ (row & 7)) * 8]);
            }
#pragma unroll
            for (int m = 0; m < 2; ++m)
#pragma unroll
                for (int nf = 0; nf < 10; ++nf)
                    bd[m][nf] = __builtin_amdgcn_mfma_f32_16x16x32_bf16(
                        afr[m][ks], bfr[nf], bd[m][nf], 0, 0, 0);
        }
#pragma unroll
        for (int m = 0; m < 2; ++m)
#pragma unroll
            for (int nf = 0; nf < 10; ++nf)
#pragma unroll
                for (int rg = 0; rg < 4; ++rg) {
                    int ldi = lq * 4 + rg + 16 * m;
                    scr[ldi * 161 + nf * 16 + l15] = __float2bfloat16(bd[m][nf][rg]);
                }

        f32x4 ac[2][8] = {};
#pragma unroll
        for (int ks = 0; ks < 2; ++ks) {
            bf16x8 bk[8];
#pragma unroll
            for (int nf = 0; nf < 8; ++nf) {
                int row = nf * 16 + l15;
                int cb = ks * 4 + lq;
                bk[nf] = *(const bf16x8*)(&Ks[row * 64 + (cb ^ (row & 7)) * 8]);
            }
#pragma unroll
            for (int m = 0; m < 2; ++m)
#pragma unroll
                for (int nf = 0; nf < 8; ++nf)
                    ac[m][nf] = __builtin_amdgcn_mfma_f32_16x16x32_bf16(
                        afw[m][ks], bk[nf], ac[m][nf], 0, 0, 0);
        }

        const bool diag = (jt == it);
#pragma unroll
        for (int m = 0; m < 2; ++m)
#pragma unroll
            for (int nf = 0; nf < 8; ++nf)
#pragma unroll
                for (int rg = 0; rg < 4; ++rg) {
                    int ldi = lq * 4 + rg + 16 * m;
                    int col = nf * 16 + l15;
                    float bdv = __bfloat162float(scr[ldi * 161 + (col + 31 - ldi)]);
                    float s = (ac[m][nf][rg] + bdv) * 0.125f;
                    if (diag && (col > dw + ldi)) s = -1e30f;
                    ac[m][nf][rg] = s;
                }

        float alpha[2][4];
#pragma unroll
        for (int m = 0; m < 2; ++m)
#pragma unroll
            for (int rg = 0; rg < 4; ++rg) {
                float v = -1e30f;
#pragma unroll
                for (int nf = 0; nf < 8; ++nf) v = fmaxf(v, ac[m][nf][rg]);
                for (int o = 8; o; o >>= 1) v = fmaxf(v, __shfl_xor(v, o));
                float mn = fmaxf(mst[m][rg], v);
                alpha[m][rg] = __expf(mst[m][rg] - mn);
                mst[m][rg] = mn;
            }
#pragma unroll
        for (int m = 0; m < 2; ++m)
#pragma unroll
            for (int nf = 0; nf < 8; ++nf)
#pragma unroll
                for (int rg = 0; rg < 4; ++rg)
                    ac[m][nf][rg] = __expf(ac[m][nf][rg] - mst[m][rg]);
#pragma unroll
        for (int m = 0; m < 2; ++m)
#pragma unroll
            for (int rg = 0; rg < 4; ++rg) {
                float sv = 0.0f;
#pragma unroll
                for (int nf = 0; nf < 8; ++nf) sv += ac[m][nf][rg];
                for (int o = 8; o; o >>= 1) sv += __shfl_xor(sv, o);
                lst[m][rg] = lst[m][rg] * alpha[m][rg] + sv;
            }
#pragma unroll
        for (int m = 0; m < 2; ++m)
#pragma unroll
            for (int nf = 0; nf < 4; ++nf)
#pragma unroll
                for (int rg = 0; rg < 4; ++rg)
                    Oacc[m][nf][rg] *= alpha[m][rg];

#pragma unroll
        for (int m = 0; m < 2; ++m)
#pragma unroll
            for (int nf = 0; nf < 8; ++nf)
#pragma unroll
                for (int rg = 0; rg < 4; ++rg) {
                    int ldi = lq * 4 + rg + 16 * m;
                    scr[ldi * 136 + nf * 16 + l15] = __float2bfloat16(ac[m][nf][rg]);
                }
#pragma unroll
        for (int ks2 = 0; ks2 < 4; ++ks2) {
            bf16x8 pa[2];
#pragma unroll
            for (int m = 0; m < 2; ++m)
                pa[m] = *(const bf16x8*)(&scr[(16 * m + l15) * 136 + ks2 * 32 + lq * 8]);
            bf16x8 vb[4];
#pragma unroll
            for (int nf = 0; nf < 4; ++nf) {
                int row = nf * 16 + l15;
                int cb = ks2 * 4 + lq;
                vb[nf] = *(const bf16x8*)(&VTs[row * 128 + (cb ^ (row & 15)) * 8]);
            }
#pragma unroll
            for (int m = 0; m < 2; ++m)
#pragma unroll
                for (int nf = 0; nf < 4; ++nf)
                    Oacc[m][nf] = __builtin_amdgcn_mfma_f32_16x16x32_bf16(
                        pa[m], vb[nf], Oacc[m][nf], 0, 0, 0);
        }
        __syncthreads();
    }

#pragma unroll
    for (int m = 0; m < 2; ++m)
#pragma unroll
        for (int rg = 0; rg < 4; ++rg) {
            float inv = 1.0f / lst[m][rg];
#pragma unroll
            for (int nf = 0; nf < 4; ++nf) {
                int row = i0 + dw + lq * 4 + rg + 16 * m;
                int col = nf * 16 + l15;
                Oa[((long)(b * S + row)) * D + n * 64 + col] =
                    __float2bfloat16(Oacc[m][nf][rg] * inv);
            }
        }
}

// ---------------- fused partial-sum + bias/residual + LayerNorm (D=1024) ----------------
// val = A0[row]+A1[row] (+bias) (+residf) (+residb); LN(val)*g+beta -> Yf/Yb
__global__ __launch_bounds__(256) void layernorm_f(const float* __restrict__ A0,
                                                   const float* __restrict__ A1,
                                                   const float* __restrict__ bias,
                                                   const float* __restrict__ residf,
                                                   const bf16* __restrict__ residb,
                                                   const float* __restrict__ g,
                                                   const float* __restrict__ beta,
                                                   float* __restrict__ Yf,
                                                   bf16* __restrict__ Yb)
{
    const int D = TD;
    long row = blockIdx.x;
    int tid = threadIdx.x;
    int wave = tid >> 6;

    float v[4], s = 0.0f;
#pragma unroll
    for (int it = 0; it < 4; ++it) {
        int c = tid + it * 256;
        float x = A0[row * D + c] + A1[row * D + c];
        if (bias)   x += bias[c];
        if (residf) x += residf[row * D + c];
        if (residb) x += __bfloat162float(residb[row * D + c]);
        v[it] = x; s += x;
    }
    for (int off = 32; off; off >>= 1) s += __shfl_xor(s, off);
    __shared__ float sm[8];
    if ((tid & 63) == 0) sm[wave] = s;
    __syncthreads();
    float mean = (sm[0] + sm[1] + sm[2] + sm[3]) * (1.0f / D);

    float var = 0.0f;
#pragma unroll
    for (int it = 0; it < 4; ++it) { float d = v[it] - mean; var += d * d; }
    for (int off = 32; off; off >>= 1) var += __shfl_xor(var, off);
    if ((tid & 63) == 0) sm[4 + wave] = var;
    __syncthreads();
    var = (sm[4] + sm[5] + sm[6] + sm[7]) * (1.0f / D);
    float rinv = rsqrtf(var + 1e-5f);

#pragma unroll
    for (int it = 0; it < 4; ++it) {
        int c = tid + it * 256;
        float o = (v[it] - mean) * rinv * g[c] + beta[c];
        if (Yf) Yf[row * D + c] = o;
        if (Yb) Yb[row * D + c] = __float2bfloat16(o);
    }
}

extern "C" void kernel_launch(void* const* d_in, const int* in_sizes, int n_in,
                              void* d_out, int out_size, void* d_ws, size_t ws_size,
                              hipStream_t stream)
{
    const float* w      = (const float*)d_in[0];
    const float* r      = (const float*)d_in[1];
    const float* w_bias = (const float*)d_in[2];
    const float* r_bias = (const float*)d_in[3];
    const float* Wq     = (const float*)d_in[4];
    const float* Wk     = (const float*)d_in[5];
    const float* Wv     = (const float*)d_in[6];
    const float* Wr     = (const float*)d_in[7];
    const float* Wo     = (const float*)d_in[8];
    const float* ln1_g  = (const float*)d_in[9];
    const float* ln1_b  = (const float*)d_in[10];
    const float* W1     = (const float*)d_in[11];
    const float* b1     = (const float*)d_in[12];
    const float* W2     = (const float*)d_in[13];
    const float* b2     = (const float*)d_in[14];
    const float* ln2_g  = (const float*)d_in[15];
    const float* ln2_b  = (const float*)d_in[16];
    float* out = (float*)d_out;

    const int  B = TB, S = TS, D = TD, NH = TNH, DH = TDH, DI = TDI;
    const long MS = (long)B * S;
    const long ND = (long)MS * D;

    char* base = (char*)d_ws;
    size_t off = 0;
    auto alloc = [&](size_t bytes) -> void* {
        void* p = base + off;
        off += (bytes + 255) & ~(size_t)255;
        return p;
    };
    bf16* wqT  = (bf16*)alloc(2UL * D * D);   // wqT..wvT contiguous = fused QKV B
    bf16* wkT  = (bf16*)alloc(2UL * D * D);
    bf16* wvT  = (bf16*)alloc(2UL * D * D);
    bf16* wrT  = (bf16*)alloc(2UL * D * D);
    bf16* woT  = (bf16*)alloc(2UL * D * D);
    bf16* w1T  = (bf16*)alloc(2UL * D * DI);
    bf16* w2T  = (bf16*)alloc(2UL * DI * D);
    bf16* bufA = (bf16*)alloc(2UL * ND);            // w_bf -> attn_vec
    bf16* bufB = (bf16*)alloc(2UL * ND);            // r_bf -> x_bf
    bf16* Qw   = (bf16*)alloc(2UL * ND);            // Qw..VT (32 MB) -> fp32 split partials
    bf16* Kb   = (bf16*)alloc(2UL * ND);
    bf16* RRb  = (bf16*)alloc(2UL * ND);
    bf16* VT   = (bf16*)alloc(2UL * ND);
    bf16* R0   = (bf16*)alloc(2UL * MS * DI);       // Vb -> h (32 MB)
    size_t need = off;
    (void)in_sizes; (void)n_in; (void)out_size;

    if (ws_size < need) {
        zero_out_k<<<dim3((unsigned)((ND + 255) / 256)), 256, 0, stream>>>(out, ND);
        return;
    }

    bf16* w_bf = bufA;  bf16* attn_vec = bufA;
    bf16* r_bf = bufB;  bf16* x_bf     = bufB;
    bf16* Vb   = R0;    bf16* h        = R0;
    float* Pf  = (float*)Qw;            // 2 x (MS*D) fp32 partials overlay Qw..VT

    auto gemm128 = [&](const bf16* A, const bf16* Bt,
                       bf16* C0, bf16* C2, bf16* C3, long ldc,
                       const float* bias, const float* rf, const bf16* rb,
                       int M, int N, int K, int mode) {
        int GY = M / BM, GX = N / 128;
        gemm_k<128><<<dim3((unsigned)(GX * GY), 1), 256, 0, stream>>>(
            A, K, 0, Bt, K, 0, C0, C2, C3, nullptr, ldc, 0, bias, rf, rb, N, K, GY, mode);
    };
    auto gemm64 = [&](const bf16* A, const bf16* Bt, bf16* C0, long ldc,
                      const float* bias, const float* rf, const bf16* rb,
                      int M, int N, int K, int mode) {
        int GY = M / BM, GX = N / 64;
        gemm_k<64><<<dim3((unsigned)(GX * GY), 1), 256, 0, stream>>>(
            A, K, 0, Bt, K, 0, C0, nullptr, nullptr, nullptr, ldc, 0, bias, rf, rb,
            N, K, GY, mode);
    };
    // split-K2, 128x128 tile, fp32 partials
    auto gemmSK2 = [&](const bf16* A, long lda, const bf16* Bt, long ldb,
                       float* Cfp, int M, int N, int K) {
        int GY = M / BM, GX = N / 128;
        int Kh = K / 2;
        gemm_k<128><<<dim3((unsigned)(GX * GY), 2), 256, 0, stream>>>(
            A, lda, Kh, Bt, ldb, Kh, nullptr, nullptr, nullptr, Cfp,
            N, (long)M * N, nullptr, nullptr, nullptr, N, Kh, GY, FP32S);
    };

    // ---- converts + weight transposes ----
    convert2_f2b<<<dim3((unsigned)(ND / (8 * 256)), 2), 256, 0, stream>>>(
        w, r, w_bf, r_bf, ND);
    transpose5_f2b<<<dim3(D / 32, D / 32, 5), 256, 0, stream>>>(
        Wq, Wk, Wv, Wr, Wo, wqT);
    transpose_f2b<<<dim3(DI / 32, D / 32), 256, 0, stream>>>(W1, w1T, D, DI);
    transpose_f2b<<<dim3(D / 32, DI / 32), 256, 0, stream>>>(W2, w2T, DI, D);

    // ---- projections ----
    gemm128(w_bf, wqT, Qw, Kb, Vb, D, w_bias, nullptr, nullptr,
            (int)MS, 3 * D, D, FQKV);
    gemm64(r_bf, wrT, RRb, D, nullptr, nullptr, nullptr, (int)MS, D, D, 0);
    transpose_v<<<dim3(S / 32, DH / 32, B * NH), 256, 0, stream>>>(Vb, VT);

    // ---- fused flash attention ----
    flash_attn<<<dim3(512), 256, 0, stream>>>(Qw, Kb, RRb, VT, w_bias, r_bias, attn_vec);

    // ---- Wo (split-K2 -> fp32 partials; Qw..VT now dead) + fused LN1 ----
    gemmSK2(attn_vec, D, woT, D, Pf, (int)MS, D, D);
    layernorm_f<<<dim3((unsigned)MS), 256, 0, stream>>>(
        Pf, Pf + MS * D, nullptr, w, nullptr, ln1_g, ln1_b, nullptr, x_bf);

    // ---- FFN ----
    gemm128(x_bf, w1T, h, nullptr, nullptr, DI, b1, nullptr, nullptr,
            (int)MS, DI, D, FRELU);
    gemmSK2(h, DI, w2T, DI, Pf, (int)MS, D, DI);
    layernorm_f<<<dim3((unsigned)MS), 256, 0, stream>>>(
        Pf, Pf + MS * D, b2, nullptr, x_bf, ln2_g, ln2_b, out, nullptr);
}